// Round 12
// baseline (586.290 us; speedup 1.0000x reference)
//
#include <hip/hip_runtime.h>
#include <hip/hip_bf16.h>
#include <math.h>

#define SUB_NO 20
#define T_NO   200
#define BASIS_NO 19
#define T_DATA 100000
#define E_NO   800
#define I_NO   200

using u16 = unsigned short;
using u32 = unsigned int;
using u64 = unsigned long long;

__device__ __forceinline__ float bf2f(u16 h) {
  return __builtin_bit_cast(float, (u32)h << 16);
}
__device__ __forceinline__ u16 f2bf(float f) {
  u32 u = __builtin_bit_cast(u32, f);
  u += 0x7FFFu + ((u >> 16) & 1u);  // RNE
  return (u16)(u >> 16);
}
__device__ __forceinline__ float ldx(const void* p, int i, bool bf) {
  return bf ? bf2f(((const u16*)p)[i]) : ((const float*)p)[i];
}
__device__ __forceinline__ void stx(void* p, int i, float v, bool bf) {
  if (bf) ((u16*)p)[i] = f2bf(v); else ((float*)p)[i] = v;
}

// packed-bf16 dot2: (a.lo,a.hi)·(b.lo,b.hi)+c, fp32 accumulate
#if defined(__clang__) && (__clang_major__ >= 17) && __has_builtin(__builtin_amdgcn_fdot2_f32_bf16)
typedef __bf16 bf16x2 __attribute__((ext_vector_type(2)));
__device__ __forceinline__ float dot2bf(u32 a, u32 b, float c) {
  return __builtin_amdgcn_fdot2_f32_bf16(__builtin_bit_cast(bf16x2, a),
                                         __builtin_bit_cast(bf16x2, b), c, false);
}
#else
__device__ __forceinline__ float dot2bf(u32 a, u32 b, float c) {
  float ax = __builtin_bit_cast(float, a << 16);
  float ay = __builtin_bit_cast(float, a & 0xFFFF0000u);
  float bx = __builtin_bit_cast(float, b << 16);
  float by = __builtin_bit_cast(float, b & 0xFFFF0000u);
  return fmaf(ay, by, fmaf(ax, bx, c));
}
#endif

// ---------------------------------------------------------------------------
// K0: cos basis -> packed bf16 kernel pairs kp[m][40]: (e_ns,i_ns) at [k],
// (e_s,i_s) at [20+k]; hist kernels (fp32); out_filters; assignment tables.
// ---------------------------------------------------------------------------
#define K0_BLOCKS 21
__global__ __launch_bounds__(256) void k0_prep(
    const u32* __restrict__ probe,  // C_den dword0: 0 -> fp32, else bf16
    const void* __restrict__ Wns, const void* __restrict__ Ws,
    const void* __restrict__ hsw, const void* __restrict__ hnsw,
    const void* __restrict__ Cse, const void* __restrict__ Csi,
    u32* __restrict__ kpair, float* __restrict__ hist_s,
    float* __restrict__ hist_ns, int* __restrict__ ae, int* __restrict__ ai,
    void* __restrict__ out) {
  const bool bf = (probe[0] != 0u);
  __shared__ float cb[BASIS_NO * T_NO];
  const int tid = threadIdx.x;
  constexpr float PI = 3.14159265358979323846f;
  for (int idx = tid; idx < BASIS_NO * T_NO; idx += 256) {
    int b = idx / T_NO, j = idx - b * T_NO;
    float phi = 0.5f * PI * (float)b;
    float raw = 5.0f * logf((float)j + 1.0f);
    float v = 0.f;
    if (raw >= phi - PI && raw <= phi + PI) v = 0.5f * cosf(raw - phi) + 0.5f;
    cb[idx] = v;
  }
  __syncthreads();
  const int fbase = 2 * T_DATA;
  for (int gid = blockIdx.x * 256 + tid; gid < 5200; gid += K0_BLOCKS * 256) {
    if (gid < 4000) {
      int k = gid / T_NO, j = gid - k * T_NO;
      float e_ns = 0.f, i_ns = 0.f, e_s = 0.f, i_s = 0.f;
#pragma unroll
      for (int b = 0; b < BASIS_NO; ++b) {
        float c = cb[b * T_NO + j];
        e_ns = fmaf(ldx(Wns, (k * BASIS_NO + b) * 2 + 0, bf), c, e_ns);
        i_ns = fmaf(ldx(Wns, (k * BASIS_NO + b) * 2 + 1, bf), c, i_ns);
        e_s  = fmaf(ldx(Ws,  (k * BASIS_NO + b) * 2 + 0, bf), c, e_s);
        i_s  = fmaf(ldx(Ws,  (k * BASIS_NO + b) * 2 + 1, bf), c, i_s);
      }
      kpair[j * 40 + k]      = (u32)f2bf(e_ns) | ((u32)f2bf(i_ns) << 16);
      kpair[j * 40 + 20 + k] = (u32)f2bf(e_s)  | ((u32)f2bf(i_s)  << 16);
      stx(out, fbase + (0 * SUB_NO + k) * T_NO + j, e_ns, bf);
      stx(out, fbase + (1 * SUB_NO + k) * T_NO + j, i_ns, bf);
      stx(out, fbase + (2 * SUB_NO + k) * T_NO + j, e_s,  bf);
      stx(out, fbase + (3 * SUB_NO + k) * T_NO + j, i_s,  bf);
    } else if (gid < 4200) {
      int j = gid - 4000;
      float hs = 0.f, hns = 0.f;
#pragma unroll
      for (int b = 0; b < BASIS_NO; ++b) {
        float c = cb[b * T_NO + j];
        hs  = fmaf(ldx(hsw,  b, bf), c, hs);
        hns = fmaf(ldx(hnsw, b, bf), c, hns);
      }
      hist_s[j] = hs; hist_ns[j] = hns;
      stx(out, fbase + 80 * T_NO + j, hns, bf);
      stx(out, fbase + 81 * T_NO + j, hs,  bf);
    } else if (gid < 5000) {
      int e = gid - 4200;
      int a = 0;
      for (int k = 0; k < SUB_NO; ++k) if (ldx(Cse, k * E_NO + e, bf) != 0.f) a = k;
      ae[e] = a;
    } else {
      int e = gid - 5000;
      int a = 0;
      for (int k = 0; k < SUB_NO; ++k) if (ldx(Csi, k * I_NO + e, bf) != 0.f) a = k;
      ai[e] = a;
    }
  }
}

// ---------------------------------------------------------------------------
// K1: wave-per-row ballot/popcount, 16 rows/wave, 2-row pipeline.
// ---------------------------------------------------------------------------
#define K1_R 64  // rows per block, 16 per wave

__device__ __forceinline__ void k1_load_bf(const void* Se, const void* Si,
                                           int t, int l, uint4& a0, uint4& a1,
                                           uint4& c0) {
  const uint4 z4 = make_uint4(0u, 0u, 0u, 0u);
  const uint4* p = (const uint4*)((const u16*)Se + (size_t)t * E_NO);
  a0 = p[l]; a1 = (l < 36) ? p[64 + l] : z4;
  const uint4* pi = (const uint4*)((const u16*)Si + (size_t)t * I_NO);
  c0 = (l < 25) ? pi[l] : z4;
}

__device__ __forceinline__ void k1_proc_bf(uint4 a0, uint4 a1, uint4 c0,
                                           const u64* rme, const u64* rmi,
                                           int l, int t,
                                           u32* __restrict__ syn_pair) {
  u32 ce = 0, ci = 0;
#pragma unroll
  for (int j = 0; j < 8; ++j) {
    u32 d = (&a0.x)[j >> 1];
    u32 h = (j & 1) ? (d >> 16) : (d & 0xFFFFu);
    u64 m = __ballot(h != 0u);
    ce += (u32)__popcll(rme[j] & m);
  }
#pragma unroll
  for (int j = 0; j < 8; ++j) {
    u32 d = (&a1.x)[j >> 1];
    u32 h = (j & 1) ? (d >> 16) : (d & 0xFFFFu);
    u64 m = __ballot(h != 0u);
    ce += (u32)__popcll(rme[8 + j] & m);
  }
#pragma unroll
  for (int j = 0; j < 8; ++j) {
    u32 d = (&c0.x)[j >> 1];
    u32 h = (j & 1) ? (d >> 16) : (d & 0xFFFFu);
    u64 m = __ballot(h != 0u);
    ci += (u32)__popcll(rmi[j] & m);
  }
  if (l < SUB_NO) {
    u32 pe = (u32)f2bf((float)ce);
    u32 pif = (u32)f2bf((float)ci);
    syn_pair[(size_t)t * SUB_NO + l] = pe | (pif << 16);
  }
}

__global__ __launch_bounds__(256, 4) void k1_agg(
    const u32* __restrict__ probe,
    const void* __restrict__ Se, const void* __restrict__ Si,
    const int* __restrict__ ae, const int* __restrict__ ai,
    u32* __restrict__ syn_pair) {
  const bool bf = (probe[0] != 0u);
  __shared__ u64 mask_e[SUB_NO][16];
  __shared__ u64 mask_i[SUB_NO][8];
  __shared__ int lae[E_NO];
  __shared__ int lai[I_NO];
  const int tid = threadIdx.x;
  const int l = tid & 63;
  const int wv = tid >> 6;
  for (int n = tid; n < E_NO; n += 256) lae[n] = ae[n];
  for (int n = tid; n < I_NO; n += 256) lai[n] = ai[n];
  __syncthreads();
  for (int pid = tid; pid < 480; pid += 256) {
    if (pid < 320) {
      int k = pid >> 4, w = pid & 15;
      u64 m = 0;
      if (bf) {
        if (w < 8) { for (int b = 0; b < 64; ++b) if (lae[8 * b + w] == k) m |= 1ull << b; }
        else       { for (int b = 0; b < 36; ++b) if (lae[512 + 8 * b + (w - 8)] == k) m |= 1ull << b; }
      } else {
        int g = w >> 2, j = w & 3;
        int lim = (g < 3) ? 64 : 8;
        for (int b = 0; b < lim; ++b) if (lae[256 * g + 4 * b + j] == k) m |= 1ull << b;
      }
      mask_e[k][w] = m;
    } else {
      int p2 = pid - 320; int k = p2 >> 3, w = p2 & 7;
      u64 m = 0;
      if (bf) { for (int b = 0; b < 25; ++b) { int e = 8 * b + w; if (e < I_NO && lai[e] == k) m |= 1ull << b; } }
      else if (w < 4) { for (int b = 0; b < 50; ++b) if (lai[4 * b + w] == k) m |= 1ull << b; }
      mask_i[k][w] = m;
    }
  }
  __syncthreads();
  u64 rme[16], rmi[8];
  const int kk = (l < SUB_NO) ? l : 0;
#pragma unroll
  for (int w = 0; w < 16; ++w) rme[w] = mask_e[kk][w];
#pragma unroll
  for (int w = 0; w < 8; ++w) rmi[w] = mask_i[kk][w];

  const int r0 = blockIdx.x * K1_R + wv * 16;
  if (r0 >= T_DATA) return;
  const uint4 z4 = make_uint4(0u, 0u, 0u, 0u);

  if (bf) {
    uint4 A0, A1, C0, B0, B1, D0;
    k1_load_bf(Se, Si, r0, l, A0, A1, C0);
    k1_load_bf(Se, Si, r0 + 1, l, B0, B1, D0);
    for (int i = 0; i < 16; i += 2) {
      uint4 N0 = z4, N1 = z4, M0 = z4, M1 = z4, P0 = z4, Q0 = z4;
      if (i + 2 < 16) {
        k1_load_bf(Se, Si, r0 + i + 2, l, N0, N1, P0);
        k1_load_bf(Se, Si, r0 + i + 3, l, M0, M1, Q0);
      }
      k1_proc_bf(A0, A1, C0, rme, rmi, l, r0 + i, syn_pair);
      k1_proc_bf(B0, B1, D0, rme, rmi, l, r0 + i + 1, syn_pair);
      A0 = N0; A1 = N1; C0 = P0;
      B0 = M0; B1 = M1; D0 = Q0;
    }
  } else {
    uint4 a0, a1, a2, a3, c0;
    {
      const uint4* p = (const uint4*)((const float*)Se + (size_t)r0 * E_NO);
      a0 = p[l]; a1 = p[64 + l]; a2 = p[128 + l]; a3 = (l < 8) ? p[192 + l] : z4;
      const uint4* pi = (const uint4*)((const float*)Si + (size_t)r0 * I_NO);
      c0 = (l < 50) ? pi[l] : z4;
    }
    for (int i = 0; i < 16; ++i) {
      const int t = r0 + i;
      uint4 b0 = z4, b1 = z4, b2 = z4, b3 = z4, d0 = z4;
      if (i + 1 < 16) {
        const uint4* p = (const uint4*)((const float*)Se + (size_t)(t + 1) * E_NO);
        b0 = p[l]; b1 = p[64 + l]; b2 = p[128 + l]; b3 = (l < 8) ? p[192 + l] : z4;
        const uint4* pi = (const uint4*)((const float*)Si + (size_t)(t + 1) * I_NO);
        d0 = (l < 50) ? pi[l] : z4;
      }
      u32 ce = 0, ci = 0;
      const uint4 va[4] = {a0, a1, a2, a3};
#pragma unroll
      for (int g = 0; g < 4; ++g) {
#pragma unroll
        for (int j = 0; j < 4; ++j) {
          u32 d = (&va[g].x)[j];
          u64 m = __ballot(d != 0u);
          ce += (u32)__popcll(rme[4 * g + j] & m);
        }
      }
#pragma unroll
      for (int j = 0; j < 4; ++j) {
        u32 d = (&c0.x)[j];
        u64 m = __ballot(d != 0u);
        ci += (u32)__popcll(rmi[j] & m);
      }
      if (l < SUB_NO) {
        u32 pe = (u32)f2bf((float)ce);
        u32 pif = (u32)f2bf((float)ci);
        syn_pair[(size_t)t * SUB_NO + l] = pe | (pif << 16);
      }
      a0 = b0; a1 = b1; a2 = b2; a3 = b3; c0 = d0;
    }
  }
}

// ---------------------------------------------------------------------------
// K2: 320 thr = 5 waves; wave kg -> subunits 4kg..4kg+3; ONE timestep per
// lane (K2T=64 -> 1563 blocks, 7.6 waves/SIMD for latency hiding).
// Conv via v_dot2_f32_bf16; coefficients via wave-uniform scalar loads.
// No barriers in the main loop. Tile region reused for tree-phase exchange.
// ---------------------------------------------------------------------------
#define K2T  64
#define K2R  (K2T + T_NO)  // 264

__global__ __launch_bounds__(320, 6) void k2_conv(
    const u32* __restrict__ probe,
    const u32* __restrict__ syn_pair, const u32* __restrict__ kpair,
    const float* __restrict__ hist_s, const float* __restrict__ hist_ns,
    const void* __restrict__ Z, const void* __restrict__ Wsub_ns,
    const void* __restrict__ Wsub_s, const void* __restrict__ Vo,
    const void* __restrict__ Thns, const void* __restrict__ Ths,
    void* __restrict__ out) {
  const bool bf = (probe[0] != 0u);
  __shared__ __align__(16) unsigned char smem[K2R * SUB_NO * 4];  // 21120 B
  uint4* tile4 = (uint4*)smem;                 // conv phase: 264 x 5 uint4
  float* accsh = (float*)smem;                 // tree phase: [64][41] = 10496 B
  float* hp    = (float*)(smem + 10496);       // hp_s[5][64] + hp_ns[5][64] = 2560 B
  __shared__ float ztile[K2R];
  __shared__ float lhs[T_NO], lhns[T_NO];
  __shared__ float ws2_l[SUB_NO], wns2_l[SUB_NO], ths_l[SUB_NO], thns_l[SUB_NO];
  const int tid = threadIdx.x;
  const int l = tid & 63;
  const int kgu = __builtin_amdgcn_readfirstlane(tid >> 6);  // wave-uniform
  const int t0 = blockIdx.x * K2T;

  const int base4 = (t0 - T_NO) * (SUB_NO / 4);
  const uint4* sp4 = (const uint4*)syn_pair;
  for (int n = tid; n < K2R * 5; n += 320) {
    int g = base4 + n;
    uint4 v = make_uint4(0u, 0u, 0u, 0u);
    if (g >= 0 && g < T_DATA * SUB_NO / 4) v = sp4[g];
    tile4[n] = v;
  }
  const int zbase = t0 - T_NO;
  for (int n = tid; n < K2R; n += 320) {
    int g = zbase + n;
    ztile[n] = (g >= 0 && g < T_DATA) ? ldx(Z, g, bf) : 0.f;
  }
  for (int n = tid; n < T_NO; n += 320) { lhs[n] = hist_s[n]; lhns[n] = hist_ns[n]; }
  if (tid < SUB_NO) {
    float w = ldx(Wsub_s, tid, bf);   ws2_l[tid]  = w * w;
    float wn = ldx(Wsub_ns, tid, bf); wns2_l[tid] = wn * wn;
    ths_l[tid]  = ldx(Ths, tid, bf);
    thns_l[tid] = ldx(Thns, tid, bf);
  }
  __syncthreads();

  float ans_a[4] = {0,0,0,0}, as_a[4] = {0,0,0,0};
  float hs_a = 0.f, hns_a = 0.f;
  const int mlo = 40 * kgu;

#pragma unroll 4
  for (int m = 0; m < T_NO; ++m) {
    // wave-uniform packed-bf16 coefficient loads (scalar cache)
    uint4 cns = *(const uint4*)(kpair + m * 40 + 4 * kgu);
    uint4 cs  = *(const uint4*)(kpair + m * 40 + 20 + 4 * kgu);
    uint4 qa = tile4[(l + T_NO - m) * 5 + kgu];
    if ((unsigned)(m - mlo) < 40u) {  // this wave's 40-tap hist share
      float za = ztile[l + T_NO - 1 - m];
      hs_a = fmaf(lhs[m], za, hs_a);
      hns_a = fmaf(lhns[m], za, hns_a);
    }
#pragma unroll
    for (int j = 0; j < 4; ++j) {
      u32 ua = (&qa.x)[j];
      ans_a[j] = dot2bf(ua, (&cns.x)[j], ans_a[j]);
      as_a[j]  = dot2bf(ua, (&cs.x)[j],  as_a[j]);
    }
  }
  __syncthreads();  // all waves done reading tile4 before overlay writes

  // exchange: accsh[t_local][41]: s at [k], ns at [20+k]; hp_s/hp_ns [5][64]
#pragma unroll
  for (int j = 0; j < 4; ++j) {
    const int k = kgu * 4 + j;
    accsh[l * 41 + k]      = as_a[j];
    accsh[l * 41 + 20 + k] = ans_a[j];
  }
  float* hp_s = hp;
  float* hp_ns = hp + 320;
  hp_s[kgu * 64 + l] = hs_a;
  hp_ns[kgu * 64 + l] = hns_a;
  __syncthreads();

  if (kgu == 0) {
    float h_s = 0.f, h_ns = 0.f;
#pragma unroll
    for (int w = 0; w < 5; ++w) { h_s += hp_s[w * 64 + l]; h_ns += hp_ns[w * 64 + l]; }
    const float* ar = &accsh[l * 41];
    float so[SUB_NO], no[SUB_NO];
#pragma unroll
    for (int k = SUB_NO - 1; k >= 1; --k) {
      float as_ = ar[k] + ths_l[k];
      float an_ = ar[20 + k] + thns_l[k];
      const int c1 = 2 * k + 1, c2 = 2 * k + 2;
      if (c1 < SUB_NO) { as_ += ws2_l[c1] * so[c1]; an_ += wns2_l[c1] * no[c1]; }
      if (c2 < SUB_NO) { as_ += ws2_l[c2] * so[c2]; an_ += wns2_l[c2] * no[c2]; }
      so[k] = tanhf(as_);
      no[k] = tanhf(an_);
    }
    float zs = h_s + ar[0] + ths_l[0] + ws2_l[1] * so[1] + ws2_l[2] * so[2];
    float zn = h_ns + ar[20] + thns_l[0] + wns2_l[1] * no[1] + wns2_l[2] * no[2];
    float fZ = 1.f / (1.f + expf(-zs));
    float fV = tanhf(zn) * wns2_l[0] + ldx(Vo, 0, bf);
    const int t = t0 + l;
    if (t < T_DATA) {
      stx(out, t, fV, bf);
      stx(out, T_DATA + t, fZ, bf);
    }
  }
}

// ---------------------------------------------------------------------------
extern "C" void kernel_launch(void* const* d_in, const int* in_sizes, int n_in,
                              void* d_out, int out_size, void* d_ws, size_t ws_size,
                              hipStream_t stream) {
  const void* Se      = d_in[0];
  const void* Si      = d_in[1];
  const void* Z       = d_in[2];
  const u32*  probe   = (const u32*)d_in[3];  // C_den dword0: 0 -> fp32, else bf16
  const void* Cse     = d_in[4];
  const void* Csi     = d_in[5];
  const void* Wns     = d_in[6];
  const void* Ws_     = d_in[7];
  const void* Wsub_ns = d_in[8];
  const void* Wsub_s  = d_in[9];
  const void* Vo      = d_in[10];
  const void* Thns    = d_in[11];
  const void* Ths     = d_in[12];
  const void* hsw     = d_in[13];
  const void* hnsw    = d_in[14];

  float* wsf      = (float*)d_ws;
  u32*   kpair    = (u32*)wsf;                // 8000 u32 ([m][40] bf16 pairs)
  float* hist_s   = wsf + 8000;               // 200 f
  float* hist_ns  = wsf + 8200;               // 200 f
  int*   ae       = (int*)(wsf + 8400);       // 800 i
  int*   ai       = (int*)(wsf + 9200);       // 200 i
  u32*   syn_pair = (u32*)(wsf + 9408);       // 2,000,000 u32 (16B-aligned)

  hipLaunchKernelGGL(k0_prep, dim3(K0_BLOCKS), dim3(256), 0, stream,
                     probe, Wns, Ws_, hsw, hnsw, Cse, Csi,
                     kpair, hist_s, hist_ns, ae, ai, d_out);
  hipLaunchKernelGGL(k1_agg, dim3((T_DATA + K1_R - 1) / K1_R), dim3(256), 0, stream,
                     probe, Se, Si, ae, ai, syn_pair);
  hipLaunchKernelGGL(k2_conv, dim3((T_DATA + K2T - 1) / K2T), dim3(320), 0, stream,
                     probe, syn_pair, kpair, hist_s, hist_ns, Z,
                     Wsub_ns, Wsub_s, Vo, Thns, Ths, d_out);
}

// Round 13
// 579.848 us; speedup vs baseline: 1.0111x; 1.0111x over previous
//
#include <hip/hip_runtime.h>
#include <hip/hip_bf16.h>
#include <math.h>

#define SUB_NO 20
#define T_NO   200
#define BASIS_NO 19
#define T_DATA 100000
#define E_NO   800
#define I_NO   200

using u16 = unsigned short;
using u32 = unsigned int;
using u64 = unsigned long long;

__device__ __forceinline__ float bf2f(u16 h) {
  return __builtin_bit_cast(float, (u32)h << 16);
}
__device__ __forceinline__ u16 f2bf(float f) {
  u32 u = __builtin_bit_cast(u32, f);
  u += 0x7FFFu + ((u >> 16) & 1u);  // RNE
  return (u16)(u >> 16);
}
__device__ __forceinline__ float ldx(const void* p, int i, bool bf) {
  return bf ? bf2f(((const u16*)p)[i]) : ((const float*)p)[i];
}
__device__ __forceinline__ void stx(void* p, int i, float v, bool bf) {
  if (bf) ((u16*)p)[i] = f2bf(v); else ((float*)p)[i] = v;
}

// packed-bf16 dot2: (a.lo,a.hi)·(b.lo,b.hi)+c, fp32 accumulate
#if defined(__clang__) && (__clang_major__ >= 17) && __has_builtin(__builtin_amdgcn_fdot2_f32_bf16)
typedef __bf16 bf16x2 __attribute__((ext_vector_type(2)));
__device__ __forceinline__ float dot2bf(u32 a, u32 b, float c) {
  return __builtin_amdgcn_fdot2_f32_bf16(__builtin_bit_cast(bf16x2, a),
                                         __builtin_bit_cast(bf16x2, b), c, false);
}
#else
__device__ __forceinline__ float dot2bf(u32 a, u32 b, float c) {
  float ax = __builtin_bit_cast(float, a << 16);
  float ay = __builtin_bit_cast(float, a & 0xFFFF0000u);
  float bx = __builtin_bit_cast(float, b << 16);
  float by = __builtin_bit_cast(float, b & 0xFFFF0000u);
  return fmaf(ay, by, fmaf(ax, bx, c));
}
#endif

// ---------------------------------------------------------------------------
// K0: cos basis -> packed bf16 kernel pairs kp[m][40]: (e_ns,i_ns) at [k],
// (e_s,i_s) at [20+k]; hist kernels (fp32); out_filters; assignment tables.
// ---------------------------------------------------------------------------
#define K0_BLOCKS 21
__global__ __launch_bounds__(256) void k0_prep(
    const u32* __restrict__ probe,  // C_den dword0: 0 -> fp32, else bf16
    const void* __restrict__ Wns, const void* __restrict__ Ws,
    const void* __restrict__ hsw, const void* __restrict__ hnsw,
    const void* __restrict__ Cse, const void* __restrict__ Csi,
    u32* __restrict__ kpair, float* __restrict__ hist_s,
    float* __restrict__ hist_ns, int* __restrict__ ae, int* __restrict__ ai,
    void* __restrict__ out) {
  const bool bf = (probe[0] != 0u);
  __shared__ float cb[BASIS_NO * T_NO];
  const int tid = threadIdx.x;
  constexpr float PI = 3.14159265358979323846f;
  for (int idx = tid; idx < BASIS_NO * T_NO; idx += 256) {
    int b = idx / T_NO, j = idx - b * T_NO;
    float phi = 0.5f * PI * (float)b;
    float raw = 5.0f * logf((float)j + 1.0f);
    float v = 0.f;
    if (raw >= phi - PI && raw <= phi + PI) v = 0.5f * cosf(raw - phi) + 0.5f;
    cb[idx] = v;
  }
  __syncthreads();
  const int fbase = 2 * T_DATA;
  for (int gid = blockIdx.x * 256 + tid; gid < 5200; gid += K0_BLOCKS * 256) {
    if (gid < 4000) {
      int k = gid / T_NO, j = gid - k * T_NO;
      float e_ns = 0.f, i_ns = 0.f, e_s = 0.f, i_s = 0.f;
#pragma unroll
      for (int b = 0; b < BASIS_NO; ++b) {
        float c = cb[b * T_NO + j];
        e_ns = fmaf(ldx(Wns, (k * BASIS_NO + b) * 2 + 0, bf), c, e_ns);
        i_ns = fmaf(ldx(Wns, (k * BASIS_NO + b) * 2 + 1, bf), c, i_ns);
        e_s  = fmaf(ldx(Ws,  (k * BASIS_NO + b) * 2 + 0, bf), c, e_s);
        i_s  = fmaf(ldx(Ws,  (k * BASIS_NO + b) * 2 + 1, bf), c, i_s);
      }
      kpair[j * 40 + k]      = (u32)f2bf(e_ns) | ((u32)f2bf(i_ns) << 16);
      kpair[j * 40 + 20 + k] = (u32)f2bf(e_s)  | ((u32)f2bf(i_s)  << 16);
      stx(out, fbase + (0 * SUB_NO + k) * T_NO + j, e_ns, bf);
      stx(out, fbase + (1 * SUB_NO + k) * T_NO + j, i_ns, bf);
      stx(out, fbase + (2 * SUB_NO + k) * T_NO + j, e_s,  bf);
      stx(out, fbase + (3 * SUB_NO + k) * T_NO + j, i_s,  bf);
    } else if (gid < 4200) {
      int j = gid - 4000;
      float hs = 0.f, hns = 0.f;
#pragma unroll
      for (int b = 0; b < BASIS_NO; ++b) {
        float c = cb[b * T_NO + j];
        hs  = fmaf(ldx(hsw,  b, bf), c, hs);
        hns = fmaf(ldx(hnsw, b, bf), c, hns);
      }
      hist_s[j] = hs; hist_ns[j] = hns;
      stx(out, fbase + 80 * T_NO + j, hns, bf);
      stx(out, fbase + 81 * T_NO + j, hs,  bf);
    } else if (gid < 5000) {
      int e = gid - 4200;
      int a = 0;
      for (int k = 0; k < SUB_NO; ++k) if (ldx(Cse, k * E_NO + e, bf) != 0.f) a = k;
      ae[e] = a;
    } else {
      int e = gid - 5000;
      int a = 0;
      for (int k = 0; k < SUB_NO; ++k) if (ldx(Csi, k * I_NO + e, bf) != 0.f) a = k;
      ai[e] = a;
    }
  }
}

// ---------------------------------------------------------------------------
// K1: wave-per-row ballot/popcount, 16 rows/wave, 2-row pipeline.
// ---------------------------------------------------------------------------
#define K1_R 64  // rows per block, 16 per wave

__device__ __forceinline__ void k1_load_bf(const void* Se, const void* Si,
                                           int t, int l, uint4& a0, uint4& a1,
                                           uint4& c0) {
  const uint4 z4 = make_uint4(0u, 0u, 0u, 0u);
  const uint4* p = (const uint4*)((const u16*)Se + (size_t)t * E_NO);
  a0 = p[l]; a1 = (l < 36) ? p[64 + l] : z4;
  const uint4* pi = (const uint4*)((const u16*)Si + (size_t)t * I_NO);
  c0 = (l < 25) ? pi[l] : z4;
}

__device__ __forceinline__ void k1_proc_bf(uint4 a0, uint4 a1, uint4 c0,
                                           const u64* rme, const u64* rmi,
                                           int l, int t,
                                           u32* __restrict__ syn_pair) {
  u32 ce = 0, ci = 0;
#pragma unroll
  for (int j = 0; j < 8; ++j) {
    u32 d = (&a0.x)[j >> 1];
    u32 h = (j & 1) ? (d >> 16) : (d & 0xFFFFu);
    u64 m = __ballot(h != 0u);
    ce += (u32)__popcll(rme[j] & m);
  }
#pragma unroll
  for (int j = 0; j < 8; ++j) {
    u32 d = (&a1.x)[j >> 1];
    u32 h = (j & 1) ? (d >> 16) : (d & 0xFFFFu);
    u64 m = __ballot(h != 0u);
    ce += (u32)__popcll(rme[8 + j] & m);
  }
#pragma unroll
  for (int j = 0; j < 8; ++j) {
    u32 d = (&c0.x)[j >> 1];
    u32 h = (j & 1) ? (d >> 16) : (d & 0xFFFFu);
    u64 m = __ballot(h != 0u);
    ci += (u32)__popcll(rmi[j] & m);
  }
  if (l < SUB_NO) {
    u32 pe = (u32)f2bf((float)ce);
    u32 pif = (u32)f2bf((float)ci);
    syn_pair[(size_t)t * SUB_NO + l] = pe | (pif << 16);
  }
}

__global__ __launch_bounds__(256, 4) void k1_agg(
    const u32* __restrict__ probe,
    const void* __restrict__ Se, const void* __restrict__ Si,
    const int* __restrict__ ae, const int* __restrict__ ai,
    u32* __restrict__ syn_pair) {
  const bool bf = (probe[0] != 0u);
  __shared__ u64 mask_e[SUB_NO][16];
  __shared__ u64 mask_i[SUB_NO][8];
  __shared__ int lae[E_NO];
  __shared__ int lai[I_NO];
  const int tid = threadIdx.x;
  const int l = tid & 63;
  const int wv = tid >> 6;
  for (int n = tid; n < E_NO; n += 256) lae[n] = ae[n];
  for (int n = tid; n < I_NO; n += 256) lai[n] = ai[n];
  __syncthreads();
  for (int pid = tid; pid < 480; pid += 256) {
    if (pid < 320) {
      int k = pid >> 4, w = pid & 15;
      u64 m = 0;
      if (bf) {
        if (w < 8) { for (int b = 0; b < 64; ++b) if (lae[8 * b + w] == k) m |= 1ull << b; }
        else       { for (int b = 0; b < 36; ++b) if (lae[512 + 8 * b + (w - 8)] == k) m |= 1ull << b; }
      } else {
        int g = w >> 2, j = w & 3;
        int lim = (g < 3) ? 64 : 8;
        for (int b = 0; b < lim; ++b) if (lae[256 * g + 4 * b + j] == k) m |= 1ull << b;
      }
      mask_e[k][w] = m;
    } else {
      int p2 = pid - 320; int k = p2 >> 3, w = p2 & 7;
      u64 m = 0;
      if (bf) { for (int b = 0; b < 25; ++b) { int e = 8 * b + w; if (e < I_NO && lai[e] == k) m |= 1ull << b; } }
      else if (w < 4) { for (int b = 0; b < 50; ++b) if (lai[4 * b + w] == k) m |= 1ull << b; }
      mask_i[k][w] = m;
    }
  }
  __syncthreads();
  u64 rme[16], rmi[8];
  const int kk = (l < SUB_NO) ? l : 0;
#pragma unroll
  for (int w = 0; w < 16; ++w) rme[w] = mask_e[kk][w];
#pragma unroll
  for (int w = 0; w < 8; ++w) rmi[w] = mask_i[kk][w];

  const int r0 = blockIdx.x * K1_R + wv * 16;
  if (r0 >= T_DATA) return;
  const uint4 z4 = make_uint4(0u, 0u, 0u, 0u);

  if (bf) {
    uint4 A0, A1, C0, B0, B1, D0;
    k1_load_bf(Se, Si, r0, l, A0, A1, C0);
    k1_load_bf(Se, Si, r0 + 1, l, B0, B1, D0);
    for (int i = 0; i < 16; i += 2) {
      uint4 N0 = z4, N1 = z4, M0 = z4, M1 = z4, P0 = z4, Q0 = z4;
      if (i + 2 < 16) {
        k1_load_bf(Se, Si, r0 + i + 2, l, N0, N1, P0);
        k1_load_bf(Se, Si, r0 + i + 3, l, M0, M1, Q0);
      }
      k1_proc_bf(A0, A1, C0, rme, rmi, l, r0 + i, syn_pair);
      k1_proc_bf(B0, B1, D0, rme, rmi, l, r0 + i + 1, syn_pair);
      A0 = N0; A1 = N1; C0 = P0;
      B0 = M0; B1 = M1; D0 = Q0;
    }
  } else {
    uint4 a0, a1, a2, a3, c0;
    {
      const uint4* p = (const uint4*)((const float*)Se + (size_t)r0 * E_NO);
      a0 = p[l]; a1 = p[64 + l]; a2 = p[128 + l]; a3 = (l < 8) ? p[192 + l] : z4;
      const uint4* pi = (const uint4*)((const float*)Si + (size_t)r0 * I_NO);
      c0 = (l < 50) ? pi[l] : z4;
    }
    for (int i = 0; i < 16; ++i) {
      const int t = r0 + i;
      uint4 b0 = z4, b1 = z4, b2 = z4, b3 = z4, d0 = z4;
      if (i + 1 < 16) {
        const uint4* p = (const uint4*)((const float*)Se + (size_t)(t + 1) * E_NO);
        b0 = p[l]; b1 = p[64 + l]; b2 = p[128 + l]; b3 = (l < 8) ? p[192 + l] : z4;
        const uint4* pi = (const uint4*)((const float*)Si + (size_t)(t + 1) * I_NO);
        d0 = (l < 50) ? pi[l] : z4;
      }
      u32 ce = 0, ci = 0;
      const uint4 va[4] = {a0, a1, a2, a3};
#pragma unroll
      for (int g = 0; g < 4; ++g) {
#pragma unroll
        for (int j = 0; j < 4; ++j) {
          u32 d = (&va[g].x)[j];
          u64 m = __ballot(d != 0u);
          ce += (u32)__popcll(rme[4 * g + j] & m);
        }
      }
#pragma unroll
      for (int j = 0; j < 4; ++j) {
        u32 d = (&c0.x)[j];
        u64 m = __ballot(d != 0u);
        ci += (u32)__popcll(rmi[j] & m);
      }
      if (l < SUB_NO) {
        u32 pe = (u32)f2bf((float)ce);
        u32 pif = (u32)f2bf((float)ci);
        syn_pair[(size_t)t * SUB_NO + l] = pe | (pif << 16);
      }
      a0 = b0; a1 = b1; a2 = b2; a3 = b3; c0 = d0;
    }
  }
}

// ---------------------------------------------------------------------------
// K2: 320 thr = 5 waves; wave kg -> subunits 4kg..4kg+3. Lane l computes TWO
// ADJACENT timesteps (t0+2l, t0+2l+1): tile is TRANSPOSED [kg][row] so lane
// reads are conflict-free (stride 32 B), and a carry register makes it ONE
// ds_read_b128 per tap for both timesteps. Coefficients via wave-uniform
// scalar loads. Tile region reused for the tree-phase exchange.
// ---------------------------------------------------------------------------
#define K2T  128
#define K2R  (K2T + T_NO)  // 328

__global__ __launch_bounds__(320, 6) void k2_conv(
    const u32* __restrict__ probe,
    const u32* __restrict__ syn_pair, const u32* __restrict__ kpair,
    const float* __restrict__ hist_s, const float* __restrict__ hist_ns,
    const void* __restrict__ Z, const void* __restrict__ Wsub_ns,
    const void* __restrict__ Wsub_s, const void* __restrict__ Vo,
    const void* __restrict__ Thns, const void* __restrict__ Ths,
    void* __restrict__ out) {
  const bool bf = (probe[0] != 0u);
  __shared__ __align__(16) unsigned char smem[K2R * SUB_NO * 4];  // 26240 B
  uint4* tileT = (uint4*)smem;                 // conv phase: [5][328] uint4
  float* accsh = (float*)smem;                 // tree phase: [128][41] = 20992 B
  float* hp    = (float*)(smem + 21000);       // hp_s[5][128]+hp_ns[5][128]=5120 B
  __shared__ float ztile[K2R];
  __shared__ float lhs[T_NO], lhns[T_NO];
  __shared__ float ws2_l[SUB_NO], wns2_l[SUB_NO], ths_l[SUB_NO], thns_l[SUB_NO];
  const int tid = threadIdx.x;
  const int l = tid & 63;
  const int kgu = __builtin_amdgcn_readfirstlane(tid >> 6);  // wave-uniform
  const int t0 = blockIdx.x * K2T;

  // stage transposed: tileT[kgt*328 + row] = syn_pair4[(t0-200+row)*5 + kgt]
  const uint4* sp4 = (const uint4*)syn_pair;
  for (int n = tid; n < 5 * K2R; n += 320) {
    int kgt = n / K2R, row = n - kgt * K2R;
    int g = t0 - T_NO + row;
    uint4 v = make_uint4(0u, 0u, 0u, 0u);
    if (g >= 0 && g < T_DATA) v = sp4[g * 5 + kgt];
    tileT[kgt * K2R + row] = v;
  }
  const int zbase = t0 - T_NO;
  for (int n = tid; n < K2R; n += 320) {
    int g = zbase + n;
    ztile[n] = (g >= 0 && g < T_DATA) ? ldx(Z, g, bf) : 0.f;
  }
  for (int n = tid; n < T_NO; n += 320) { lhs[n] = hist_s[n]; lhns[n] = hist_ns[n]; }
  if (tid < SUB_NO) {
    float w = ldx(Wsub_s, tid, bf);   ws2_l[tid]  = w * w;
    float wn = ldx(Wsub_ns, tid, bf); wns2_l[tid] = wn * wn;
    ths_l[tid]  = ldx(Ths, tid, bf);
    thns_l[tid] = ldx(Thns, tid, bf);
  }
  __syncthreads();

  float ans_a[4] = {0,0,0,0}, as_a[4] = {0,0,0,0};  // t = t0+2l
  float ans_b[4] = {0,0,0,0}, as_b[4] = {0,0,0,0};  // t = t0+2l+1
  float hs_a = 0.f, hns_a = 0.f, hs_b = 0.f, hns_b = 0.f;
  const int mlo = 40 * kgu;
  const uint4* myrow = &tileT[kgu * K2R + 2 * l];  // + (200 - m) indexed below

  uint4 carry = myrow[T_NO + 1];  // row 2l+201: t=2l+1 at m=0

#pragma unroll 4
  for (int m = 0; m < T_NO; ++m) {
    uint4 fresh = myrow[T_NO - m];  // row 2l+200-m: t=2l at tap m
    // wave-uniform packed-bf16 coefficient loads (scalar cache)
    uint4 cns = *(const uint4*)(kpair + m * 40 + 4 * kgu);
    uint4 cs  = *(const uint4*)(kpair + m * 40 + 20 + 4 * kgu);
    if ((unsigned)(m - mlo) < 40u) {  // this wave's 40-tap hist share
      float ls = lhs[m], lns = lhns[m];
      float za = ztile[2 * l + T_NO - 1 - m];
      float zb = ztile[2 * l + T_NO - m];
      hs_a = fmaf(ls, za, hs_a);   hns_a = fmaf(lns, za, hns_a);
      hs_b = fmaf(ls, zb, hs_b);   hns_b = fmaf(lns, zb, hns_b);
    }
#pragma unroll
    for (int j = 0; j < 4; ++j) {
      u32 ua = (&fresh.x)[j], ub = (&carry.x)[j];
      u32 cn = (&cns.x)[j], c2 = (&cs.x)[j];
      ans_a[j] = dot2bf(ua, cn, ans_a[j]);
      as_a[j]  = dot2bf(ua, c2, as_a[j]);
      ans_b[j] = dot2bf(ub, cn, ans_b[j]);
      as_b[j]  = dot2bf(ub, c2, as_b[j]);
    }
    carry = fresh;
  }
  __syncthreads();  // all waves done reading tileT before overlay writes

  // exchange: accsh[tl][41]: s at [k], ns at [20+k]; hp_s/hp_ns [5][128]
#pragma unroll
  for (int j = 0; j < 4; ++j) {
    const int k = kgu * 4 + j;
    accsh[(2 * l) * 41 + k]          = as_a[j];
    accsh[(2 * l) * 41 + 20 + k]     = ans_a[j];
    accsh[(2 * l + 1) * 41 + k]      = as_b[j];
    accsh[(2 * l + 1) * 41 + 20 + k] = ans_b[j];
  }
  float* hp_s = hp;
  float* hp_ns = hp + 640;
  hp_s[kgu * 128 + 2 * l] = hs_a;   hp_s[kgu * 128 + 2 * l + 1] = hs_b;
  hp_ns[kgu * 128 + 2 * l] = hns_a; hp_ns[kgu * 128 + 2 * l + 1] = hns_b;
  __syncthreads();

  if (kgu < 2) {
    const int tl = kgu * 64 + l;
    float h_s = 0.f, h_ns = 0.f;
#pragma unroll
    for (int w = 0; w < 5; ++w) { h_s += hp_s[w * 128 + tl]; h_ns += hp_ns[w * 128 + tl]; }
    const float* ar = &accsh[tl * 41];
    float so[SUB_NO], no[SUB_NO];
#pragma unroll
    for (int k = SUB_NO - 1; k >= 1; --k) {
      float as_ = ar[k] + ths_l[k];
      float an_ = ar[20 + k] + thns_l[k];
      const int c1 = 2 * k + 1, c2 = 2 * k + 2;
      if (c1 < SUB_NO) { as_ += ws2_l[c1] * so[c1]; an_ += wns2_l[c1] * no[c1]; }
      if (c2 < SUB_NO) { as_ += ws2_l[c2] * so[c2]; an_ += wns2_l[c2] * no[c2]; }
      so[k] = tanhf(as_);
      no[k] = tanhf(an_);
    }
    float zs = h_s + ar[0] + ths_l[0] + ws2_l[1] * so[1] + ws2_l[2] * so[2];
    float zn = h_ns + ar[20] + thns_l[0] + wns2_l[1] * no[1] + wns2_l[2] * no[2];
    float fZ = 1.f / (1.f + expf(-zs));
    float fV = tanhf(zn) * wns2_l[0] + ldx(Vo, 0, bf);
    const int t = t0 + tl;
    if (t < T_DATA) {
      stx(out, t, fV, bf);
      stx(out, T_DATA + t, fZ, bf);
    }
  }
}

// ---------------------------------------------------------------------------
extern "C" void kernel_launch(void* const* d_in, const int* in_sizes, int n_in,
                              void* d_out, int out_size, void* d_ws, size_t ws_size,
                              hipStream_t stream) {
  const void* Se      = d_in[0];
  const void* Si      = d_in[1];
  const void* Z       = d_in[2];
  const u32*  probe   = (const u32*)d_in[3];  // C_den dword0: 0 -> fp32, else bf16
  const void* Cse     = d_in[4];
  const void* Csi     = d_in[5];
  const void* Wns     = d_in[6];
  const void* Ws_     = d_in[7];
  const void* Wsub_ns = d_in[8];
  const void* Wsub_s  = d_in[9];
  const void* Vo      = d_in[10];
  const void* Thns    = d_in[11];
  const void* Ths     = d_in[12];
  const void* hsw     = d_in[13];
  const void* hnsw    = d_in[14];

  float* wsf      = (float*)d_ws;
  u32*   kpair    = (u32*)wsf;                // 8000 u32 ([m][40] bf16 pairs)
  float* hist_s   = wsf + 8000;               // 200 f
  float* hist_ns  = wsf + 8200;               // 200 f
  int*   ae       = (int*)(wsf + 8400);       // 800 i
  int*   ai       = (int*)(wsf + 9200);       // 200 i
  u32*   syn_pair = (u32*)(wsf + 9408);       // 2,000,000 u32 (16B-aligned)

  hipLaunchKernelGGL(k0_prep, dim3(K0_BLOCKS), dim3(256), 0, stream,
                     probe, Wns, Ws_, hsw, hnsw, Cse, Csi,
                     kpair, hist_s, hist_ns, ae, ai, d_out);
  hipLaunchKernelGGL(k1_agg, dim3((T_DATA + K1_R - 1) / K1_R), dim3(256), 0, stream,
                     probe, Se, Si, ae, ai, syn_pair);
  hipLaunchKernelGGL(k2_conv, dim3((T_DATA + K2T - 1) / K2T), dim3(320), 0, stream,
                     probe, syn_pair, kpair, hist_s, hist_ns, Z,
                     Wsub_ns, Wsub_s, Vo, Thns, Ths, d_out);
}